// Round 3
// baseline (683.386 us; speedup 1.0000x reference)
//
#include <hip/hip_runtime.h>
#include <math.h>

#define T_STEPS 1440
#define C_CHUNKS 20
#define L_STEPS 72            // 1440 / 20
#define NQ 18                 // float4 outputs per chunk (72/4)

__device__ __forceinline__ float sigf(float x) { return 1.0f / (1.0f + expf(-x)); }

struct Coefs {
    float a1, b1, b2, ksi, kse, kh;
};

__device__ __forceinline__ Coefs make_coefs(const float* p_ri, const float* p_re,
                                            const float* p_ci, const float* p_ce,
                                            const float* p_ai, const float* p_ae,
                                            const float* p_hg) {
    const float Ri = 1.0e-4f + (0.2f - 1.0e-4f) * sigf(p_ri[0]);
    const float Re = 1.0e-4f + (0.2f - 1.0e-4f) * sigf(p_re[0]);
    const float Ci = 1.0e5f + (1.0e8f - 1.0e5f) * sigf(p_ci[0]);
    const float Ce = 1.0e5f + (1.0e8f - 1.0e5f) * sigf(p_ce[0]);
    const float Ai = 0.2f * sigf(p_ai[0]);
    const float Ae = 0.2f * sigf(p_ae[0]);
    const float hg = 1.0f + (20000.0f - 1.0f) * sigf(p_hg[0]);
    const float DT = 300.0f;
    Coefs k;
    k.a1  = DT / (Ri * Ci);
    k.b1  = DT / (Ri * Ce);
    k.b2  = DT / (Re * Ce);
    k.ksi = DT * Ai / Ci;
    k.kse = DT * Ae / Ce;
    k.kh  = -DT * hg / Ci;    // MODE_COOL
    return k;
}

// 4 recurrence steps on a register quad; emits one float4 of preds
__device__ __forceinline__ void step4(const float4 (&x)[4], float& lx, float& ly,
                                      const Coefs& k, float4& o) {
    float ox[4];
#pragma unroll
    for (int j = 0; j < 4; ++j) {
        float nx = fmaf(k.a1, ly - lx, lx);
        nx = fmaf(k.ksi, x[j].w, nx);
        nx = fmaf(k.kh,  x[j].z, nx);
        float ny = fmaf(k.b1, lx - ly, ly);
        ny = fmaf(k.b2, x[j].y - ly, ny);
        ny = fmaf(k.kse, x[j].w, ny);
        lx = nx; ly = ny;
        ox[j] = nx;
    }
    o = make_float4(ox[0], ox[1], ox[2], ox[3]);
}

// ---------------- Pass 1: per-chunk local scan from zero state ----------------
__global__ __launch_bounds__(256) void rc_pass1(
    const float4* __restrict__ in,
    const float* __restrict__ p_ri, const float* __restrict__ p_re,
    const float* __restrict__ p_ci, const float* __restrict__ p_ce,
    const float* __restrict__ p_ai, const float* __restrict__ p_ae,
    const float* __restrict__ p_hg,
    float4* __restrict__ out, float2* __restrict__ dst, int B)
{
    const int tid = blockIdx.x * blockDim.x + threadIdx.x;
    if (tid >= B * C_CHUNKS) return;
    const int b = tid / C_CHUNKS;
    const int c = tid - b * C_CHUNKS;

    const Coefs k = make_coefs(p_ri, p_re, p_ci, p_ce, p_ai, p_ae, p_hg);

    const float4* p = in + (size_t)b * T_STEPS + (size_t)c * L_STEPS;
    float4* ob = out + (size_t)b * (T_STEPS / 4) + (size_t)c * NQ;

    float4 A[4], Bf[4];
#pragma unroll
    for (int j = 0; j < 4; ++j) A[j] = p[j];
#pragma unroll
    for (int j = 0; j < 4; ++j) Bf[j] = p[4 + j];

    float lx = 0.0f, ly = 0.0f;
    if (c == 0) {               // chunk 0 runs from the TRUE initial state
        lx = A[0].x;
        ly = 0.5f * (A[0].x + A[0].y);
    }

#pragma unroll
    for (int g = 0; g < NQ; g += 2) {
        float4 o;
        step4(A, lx, ly, k, o);
        if (g + 2 < NQ) {
            const float4* q = p + (size_t)(g + 2) * 4;
#pragma unroll
            for (int j = 0; j < 4; ++j) A[j] = q[j];
        }
        ob[g] = o;
        step4(Bf, lx, ly, k, o);
        if (g + 3 < NQ) {
            const float4* q = p + (size_t)(g + 3) * 4;
#pragma unroll
            for (int j = 0; j < 4; ++j) Bf[j] = q[j];
        }
        ob[g + 1] = o;
    }
    dst[(size_t)c * B + b] = make_float2(lx, ly);  // local final state d_c
}

// ---------------- Pass 2: per-sequence scan over chunk summaries ----------------
__global__ __launch_bounds__(256) void rc_pass2(
    const float2* __restrict__ dst, float2* __restrict__ sin_,
    const float* __restrict__ p_ri, const float* __restrict__ p_re,
    const float* __restrict__ p_ci, const float* __restrict__ p_ce,
    const float* __restrict__ p_ai, const float* __restrict__ p_ae,
    const float* __restrict__ p_hg, int B)
{
    const int b = blockIdx.x * blockDim.x + threadIdx.x;
    if (b >= B) return;
    const Coefs k = make_coefs(p_ri, p_re, p_ci, p_ce, p_ai, p_ae, p_hg);

    const float m00 = 1.0f - k.a1, m01 = k.a1;
    const float m10 = k.b1, m11 = 1.0f - k.b1 - k.b2;

    // E = M^L  (uniform; redundant per thread, trivial cost)
    // BUGFIX r2: identity init had e11 = 0 (dropped the t_env column of M^L)
    float e00 = 1.0f, e01 = 0.0f, e10 = 0.0f, e11 = 1.0f;
    for (int i = 0; i < L_STEPS; ++i) {
        float f00 = m00 * e00 + m01 * e10;
        float f01 = m00 * e01 + m01 * e11;
        float f10 = m10 * e00 + m11 * e10;
        float f11 = m10 * e01 + m11 * e11;
        e00 = f00; e01 = f01; e10 = f10; e11 = f11;
    }

    // chunk 0 ran from true initial state -> d_0 is the true state at t=L
    float2 d0 = dst[b];
    float sx = d0.x, sy = d0.y;         // sigma_1
    sin_[b] = make_float2(0.0f, 0.0f);  // chunk 0 needs no fixup
    for (int c = 1; c < C_CHUNKS; ++c) {
        sin_[(size_t)c * B + b] = make_float2(sx, sy);
        float2 dc = dst[(size_t)c * B + b];
        float nx = e00 * sx + e01 * sy + dc.x;
        float ny = e10 * sx + e11 * sy + dc.y;
        sx = nx; sy = ny;
    }
}

// ---------------- Pass 3: homogeneous fix-up, in-place on out ----------------
__global__ __launch_bounds__(256) void rc_pass3(
    float4* __restrict__ io, const float2* __restrict__ sin_,
    const float* __restrict__ p_ri, const float* __restrict__ p_re,
    const float* __restrict__ p_ci, const float* __restrict__ p_ce,
    const float* __restrict__ p_ai, const float* __restrict__ p_ae,
    const float* __restrict__ p_hg, int B)
{
    const int tid = blockIdx.x * blockDim.x + threadIdx.x;
    if (tid >= B * C_CHUNKS) return;
    const int b = tid / C_CHUNKS;
    const int c = tid - b * C_CHUNKS;

    const Coefs k = make_coefs(p_ri, p_re, p_ci, p_ce, p_ai, p_ae, p_hg);

    float2 s = sin_[(size_t)c * B + b];
    float vx = s.x, vy = s.y;           // v_0 = sigma_c ; (0,0) for c==0

    float4* ob = io + (size_t)b * (T_STEPS / 4) + (size_t)c * NQ;

#pragma unroll 3
    for (int q = 0; q < NQ; ++q) {
        float4 t = ob[q];
        float f[4];
#pragma unroll
        for (int u = 0; u < 4; ++u) {
            float nvx = fmaf(k.a1, vy - vx, vx);
            float nvy = fmaf(-k.b2, vy, fmaf(k.b1, vx - vy, vy));
            vx = nvx; vy = nvy;
            f[u] = vx;                   // v_{j+1}[0]
        }
        t.x += f[0]; t.y += f[1]; t.z += f[2]; t.w += f[3];
        ob[q] = t;
    }
}

extern "C" void kernel_launch(void* const* d_in, const int* in_sizes, int n_in,
                              void* d_out, int out_size, void* d_ws, size_t ws_size,
                              hipStream_t stream) {
    const float4* in = (const float4*)d_in[0];
    const float* p_ri = (const float*)d_in[1];
    const float* p_re = (const float*)d_in[2];
    const float* p_ci = (const float*)d_in[3];
    const float* p_ce = (const float*)d_in[4];
    const float* p_ai = (const float*)d_in[5];
    const float* p_ae = (const float*)d_in[6];
    const float* p_hg = (const float*)d_in[7];
    float4* out = (float4*)d_out;

    const int B = in_sizes[0] / (T_STEPS * 4);   // 16384

    float2* dst  = (float2*)d_ws;                        // B*C chunk end-states
    float2* sin_ = dst + (size_t)B * C_CHUNKS;           // B*C chunk in-states

    const int threads1 = B * C_CHUNKS;
    const int grid1 = (threads1 + 255) / 256;
    const int grid2 = (B + 255) / 256;

    rc_pass1<<<grid1, 256, 0, stream>>>(in, p_ri, p_re, p_ci, p_ce, p_ai, p_ae, p_hg,
                                        out, dst, B);
    rc_pass2<<<grid2, 256, 0, stream>>>(dst, sin_, p_ri, p_re, p_ci, p_ce, p_ai, p_ae,
                                        p_hg, B);
    rc_pass3<<<grid1, 256, 0, stream>>>(out, sin_, p_ri, p_re, p_ci, p_ce, p_ai, p_ae,
                                        p_hg, B);
}